// Round 18
// baseline (3763.037 us; speedup 1.0000x reference)
//
#include <hip/hip_runtime.h>
#include <cstdint>

#define NBATCH 128
#define NT 512
#define NT1 513
#define NS 64
#define NU 512
#define NBW 16                               // batches per workgroup
#define KF_SHORTS 16384                      // shorts per kf across the WG (32k x 512u)
#define KF_V8 (KF_SHORTS / 8)                // short8 per kf = 2048
#define PACK_SHORTS (16 * KF_SHORTS)         // 512 KB
#define CIOG_BYTES ((size_t)NT1 * NBATCH * NU * 4)   // [t][b][u]: 134,479,872
#define KF_ST 12                             // kf 0..11 -> L2->VGPR stream (2-slot pipeline)
#define KF_LD 4                              // kf 12..15 -> LDS-resident (128 KB)
#define DYN_LDS (KF_LD * KF_SHORTS * 2)      // 131072 B

typedef __attribute__((ext_vector_type(8))) short short8_t;
typedef __attribute__((ext_vector_type(4))) float f32x4;

__device__ __forceinline__ float sigf(float z) {
    return 1.0f / (1.0f + __expf(-z));
}
__device__ __forceinline__ float tanh_fast(float z) {
    return 2.0f / (1.0f + __expf(-2.0f * z)) - 1.0f;
}
__device__ __forceinline__ uint32_t bf16_top(float f) {   // RNE, result in top 16 bits
    uint32_t u = __float_as_uint(f);
    u += 0x7FFFu + ((u >> 16) & 1u);
    return u & 0xFFFF0000u;
}
__device__ __forceinline__ float f_from_lo(uint32_t p) { return __uint_as_float(p << 16); }
__device__ __forceinline__ float f_from_hi(uint32_t p) { return __uint_as_float(p & 0xFFFF0000u); }

// ---------------------------------------------------------------------------
// pack_kernel (16-wave layout): W_ig (f32 [k][u]) -> bf16 fragment order
// pack[kf][wv(16)][nf(2)][lane][j].
// value = bf16(W_ig[(kf*32 + (lane>>4)*8 + j)*512 + wv*32 + nf*16 + (lane&15)])
// ---------------------------------------------------------------------------
__global__ __launch_bounds__(512) void pack_kernel(
    const float* __restrict__ W_ig, short* __restrict__ pack)
{
    const int g = blockIdx.x * 512 + threadIdx.x;   // 32768 threads
    const int lane = g & 63;
    const int nf = (g >> 6) & 1;
    const int wv = (g >> 7) & 15;
    const int kf = g >> 11;
    const int r16 = lane & 15, kg = lane >> 4;
    const int u = wv * 32 + nf * 16 + r16;
    const int kb = kf * 32 + kg * 8;
    short8_t w;
    #pragma unroll
    for (int j = 0; j < 8; ++j) {
        w[j] = (short)(bf16_top(W_ig[(size_t)(kb + j) * NU + u]) >> 16);
    }
    *(short8_t*)(pack + (size_t)g * 8) = w;
}

// ---------------------------------------------------------------------------
// ff_kernel: feedforward gates -> packed bf16 (ci lo, og hi), t-major [t][b][u]
// (validated rounds 5-17).
// ---------------------------------------------------------------------------
__global__ __launch_bounds__(512) void ff_kernel(
    const float* __restrict__ states, const int* __restrict__ actions,
    const float* __restrict__ W_ci, const float* __restrict__ b_ci,
    const float* __restrict__ W_og, const float* __restrict__ b_og,
    uint32_t* __restrict__ ciog)
{
    __shared__ __align__(16) float sh_s[32][64];
    __shared__ int sh_a[32];
    const int tid = threadIdx.x;
    const int b = blockIdx.x / 17;
    const int t0 = (blockIdx.x % 17) * 32;
    const int tcnt = (t0 + 32 <= NT1) ? 32 : (NT1 - t0);

    const float* sp = states + ((size_t)b * NT1 + t0) * NS;
    for (int j = tid; j < tcnt * 16; j += 512) {
        const float4 v = *(const float4*)(sp + j * 4);
        *(float4*)&sh_s[j >> 4][(j & 15) * 4] = v;
    }
    for (int tt = tid; tt < tcnt; tt += 512) {
        const int t = t0 + tt;
        sh_a[tt] = (t < NT) ? actions[b * NT + t] : -1;
    }
    __syncthreads();

    const int u = tid;
    float accc[32], acco[32];
    const float bc = b_ci[u], bo = b_og[u];
    #pragma unroll
    for (int tt = 0; tt < 32; ++tt) { accc[tt] = bc; acco[tt] = bo; }

    for (int i = 0; i < NS; ++i) {
        const float wc = W_ci[(size_t)i * NU + u];
        const float wo = W_og[(size_t)i * NU + u];
        #pragma unroll
        for (int tt = 0; tt < 32; ++tt) {
            const float s = sh_s[tt][i];
            accc[tt] = fmaf(s, wc, accc[tt]);
            acco[tt] = fmaf(s, wo, acco[tt]);
        }
    }
    #pragma unroll
    for (int tt = 0; tt < 32; ++tt) {
        if (tt < tcnt) {
            float zc = accc[tt], zo = acco[tt];
            const int a = sh_a[tt];
            if (a >= 0) {
                zc += W_ci[(size_t)(NS + a) * NU + u];
                zo += W_og[(size_t)(NS + a) * NU + u];
            }
            const float ci = tanh_fast(zc);
            const float og = sigf(zo);
            ciog[((size_t)(t0 + tt) * NBATCH + b) * NU + u] = bf16_top(og) | (bf16_top(ci) >> 16);
        }
    }
}

// ---------------------------------------------------------------------------
// rec_wide: r15's validated 2-slot streamer widened to 1024 threads
// (16 waves = 4 waves/SIMD). Each wave owns a 32-u slice (2 nf fragments):
// per-wave register demand halves (~80 < the 128 cap at 4 waves/SIMD) AND
// 4-deep wave interleave hides the L2 stream latency that left r15 ~60%
// stalled (r15: per-active-CU VALU 28%, MFMA 16%). Stream volume, MFMA
// count, swizzle, numerics unchanged. pk loads stay mid-stream (r17 showed
// post-barrier placement costs ~1 us/step). 2 barriers/step.
// ---------------------------------------------------------------------------
__global__ __launch_bounds__(1024) void rec_wide(
    const short* __restrict__ pack,
    const float* __restrict__ b_ig, const float* __restrict__ W_lin,
    const float* __restrict__ b_lin,
    const uint32_t* __restrict__ ciog,   // [t][b][u]
    float* __restrict__ out)
{
    extern __shared__ __align__(16) char dynsm[];      // 128KB: W kf12..15
    __shared__ __align__(16) short hsh[NBW * NU];      // 16KB single buffer
    __shared__ float ysum[2][16][NBW];

    const int tid  = threadIdx.x;
    const int lane = tid & 63;
    const int wv   = tid >> 6;      // wave 0..15, owns u in [wv*32, +32)
    const int n0   = wv << 5;
    const int r16  = lane & 15;
    const int kg   = lane >> 4;
    const int b0   = blockIdx.x * NBW;

    const short8_t* pr = (const short8_t*)pack;
    #define PIDX(KF_, NF_) (((((KF_) * 16) + wv) * 2 + (NF_)) * 64 + lane)
    #define LD2(S_, KF_) { (S_)[0] = pr[PIDX(KF_, 0)]; (S_)[1] = pr[PIDX(KF_, 1)]; }

    // ---- one-time: kf12..15 into LDS (linear copy, layout == pack) ----
    short8_t* dl = (short8_t*)dynsm;
    {
        const short8_t* pl = pr + KF_ST * KF_V8;
        #pragma unroll
        for (int i = 0; i < 8; ++i) dl[i * 1024 + tid] = pl[i * 1024 + tid];
    }

    float big[2], wl[2];
    #pragma unroll
    for (int nf = 0; nf < 2; ++nf) {
        big[nf] = b_ig[n0 + nf * 16 + r16];
        wl[nf]  = W_lin[n0 + nf * 16 + r16];
    }
    const float blin = b_lin[0];

    for (int i = tid; i < NBW * NU; i += 1024) hsh[i] = 0;

    float cst[2][4] = {{0.f,0.f,0.f,0.f},{0.f,0.f,0.f,0.f}};

    const int amask = (r16 & 7) << 4;    // XOR swizzle (validated r2-r17)
    const char* hb = (const char*)hsh;
    char* hw = (char*)hsh;

    // ---- stream prologue: S0 <- kf0, S1 <- kf1 ----
    short8_t S0[2], S1[2];
    LD2(S0, 0) LD2(S1, 1)

    __syncthreads();

    for (int t = 0; t < NT1; ++t) {
        // previous step's output row (ysum double-buffered)
        if (t > 0 && wv == 0 && lane < NBW) {
            float y = blin;
            #pragma unroll
            for (int w16 = 0; w16 < 16; ++w16) y += ysum[(t - 1) & 1][w16][lane];
            out[(size_t)(b0 + lane) * NT1 + (t - 1)] = y;
        }

        f32x4 acc[2];
        #pragma unroll
        for (int nf = 0; nf < 2; ++nf) { acc[nf][0]=0.f; acc[nf][1]=0.f; acc[nf][2]=0.f; acc[nf][3]=0.f; }

        #define AFRAG(KF) (*(const short8_t*)(hb + r16 * 1024 + ((((KF) * 64) + kg * 16) ^ amask)))
        #define MF2(KF, W) { const short8_t a_ = AFRAG(KF); \
            acc[0] = __builtin_amdgcn_mfma_f32_16x16x32_bf16(a_, (W)[0], acc[0], 0, 0, 0); \
            acc[1] = __builtin_amdgcn_mfma_f32_16x16x32_bf16(a_, (W)[1], acc[1], 0, 0, 0); }

        // ---- streamed phases 0..11: consume slot, refill with kf+2 ----
        MF2(0,  S0)  LD2(S0, 2)
        MF2(1,  S1)  LD2(S1, 3)
        MF2(2,  S0)  LD2(S0, 4)
        MF2(3,  S1)  LD2(S1, 5)
        MF2(4,  S0)  LD2(S0, 6)
        MF2(5,  S1)  LD2(S1, 7)
        MF2(6,  S0)  LD2(S0, 8)
        MF2(7,  S1)  LD2(S1, 9)

        // ci/og loads for this step (mid-stream: latency hidden; r15 position)
        uint32_t pk[2][4];
        {
            const uint32_t* cg = ciog + (size_t)t * (NBATCH * NU);
            #pragma unroll
            for (int nf = 0; nf < 2; ++nf) {
                #pragma unroll
                for (int j = 0; j < 4; ++j)
                    pk[nf][j] = cg[(size_t)(b0 + kg * 4 + j) * NU + n0 + nf * 16 + r16];
            }
        }

        MF2(8,  S0)  LD2(S0, 10)
        MF2(9,  S1)  LD2(S1, 11)
        MF2(10, S0)  LD2(S0, 0)   // wrap: next step's kf0 (same bytes, W const)
        MF2(11, S1)  LD2(S1, 1)

        // ---- LDS-resident phases kf12..15 ----
        #pragma unroll
        for (int kf = 0; kf < KF_LD; ++kf) {
            short8_t wt[2];
            #pragma unroll
            for (int nf = 0; nf < 2; ++nf)
                wt[nf] = dl[((kf * 16 + wv) * 2 + nf) * 64 + lane];
            MF2(KF_ST + kf, wt)
        }
        #undef MF2
        #undef AFRAG

        __syncthreads();   // barrier 1: all h reads of this step done

        // ---- gate phase: c update, h_{t+1} write (same buffer, now safe) ----
        float yp[4] = {0.f, 0.f, 0.f, 0.f};
        #pragma unroll
        for (int nf = 0; nf < 2; ++nf) {
            const int u2 = (n0 + nf * 16 + r16) * 2;
            #pragma unroll
            for (int j = 0; j < 4; ++j) {
                const int b = kg * 4 + j;
                const float z   = acc[nf][j] + big[nf];
                const float igv = sigf(z);
                const uint32_t p = pk[nf][j];
                cst[nf][j] = fmaf(f_from_lo(p), igv, cst[nf][j]);
                const float hv = cst[nf][j] * f_from_hi(p);
                yp[j] = fmaf(hv, wl[nf], yp[j]);
                const int wb = b * 1024 + (u2 ^ ((b & 7) << 4));
                *(short*)(hw + wb) = (short)(bf16_top(hv) >> 16);
            }
        }

        #pragma unroll
        for (int m = 1; m <= 8; m <<= 1) {
            yp[0] += __shfl_xor(yp[0], m);
            yp[1] += __shfl_xor(yp[1], m);
            yp[2] += __shfl_xor(yp[2], m);
            yp[3] += __shfl_xor(yp[3], m);
        }
        if (r16 == 0) {
            #pragma unroll
            for (int j = 0; j < 4; ++j) ysum[t & 1][wv][kg * 4 + j] = yp[j];
        }

        __syncthreads();   // barrier 2: h_{t+1} + ysum visible
    }

    if (wv == 0 && lane < NBW) {
        float y = blin;
        #pragma unroll
        for (int w16 = 0; w16 < 16; ++w16) y += ysum[0][w16][lane];
        out[(size_t)(b0 + lane) * NT1 + NT] = y;
    }
    #undef LD2
    #undef PIDX
}

// ---------------------------------------------------------------------------
// Fallback (ws too small): validated round-1 kernel.
// ---------------------------------------------------------------------------
__device__ __forceinline__ void fma4(float4& acc, const float4 w, const float s) {
    acc.x = fmaf(w.x, s, acc.x);
    acc.y = fmaf(w.y, s, acc.y);
    acc.z = fmaf(w.z, s, acc.z);
    acc.w = fmaf(w.w, s, acc.w);
}

__global__ __launch_bounds__(512) void rec_fallback(
    const float* __restrict__ states, const int* __restrict__ actions,
    const float* __restrict__ W_ci, const float* __restrict__ b_ci,
    const float* __restrict__ W_ig, const float* __restrict__ b_ig,
    const float* __restrict__ W_og, const float* __restrict__ b_og,
    const float* __restrict__ W_lin, const float* __restrict__ b_lin,
    float* __restrict__ out)
{
    __shared__ __align__(16) float h_lds[2][NU];
    __shared__ __align__(16) float part[4][2][NU];
    __shared__ float ysum[8][2];
    __shared__ float x_lds[2][NS];
    __shared__ int a_lds[2];

    const int tid = threadIdx.x;
    const int b0 = blockIdx.x * 2;
    const int uq = tid & 127;
    const int kq = tid >> 7;
    const int k0 = kq << 7;

    h_lds[0][tid] = 0.0f;
    h_lds[1][tid] = 0.0f;
    float c0 = 0.0f, c1 = 0.0f;
    const float wlin = W_lin[tid];
    const float big_ = b_ig[tid];
    const float blin = b_lin[0];
    const float bc = b_ci[tid], bo = b_og[tid];
    __syncthreads();

    for (int t = 0; t < NT1; ++t) {
        if (tid < 128) {
            const int bb = tid >> 6, i = tid & 63;
            x_lds[bb][i] = states[((size_t)(b0 + bb) * NT1 + t) * NS + i];
        } else if (tid < 130) {
            const int bb = tid - 128;
            a_lds[bb] = (t < NT) ? actions[(b0 + bb) * NT + t] : -1;
        }

        float4 a0 = make_float4(0.f, 0.f, 0.f, 0.f);
        float4 a1 = make_float4(0.f, 0.f, 0.f, 0.f);
        for (int kk = 0; kk < 128; kk += 4) {
            const int k = k0 + kk;
            const float4 h0v = *(const float4*)&h_lds[0][k];
            const float4 h1v = *(const float4*)&h_lds[1][k];
            const float* wr = W_ig + (size_t)k * NU + (uq << 2);
            const float4 w0 = *(const float4*)(wr);
            const float4 w1 = *(const float4*)(wr + NU);
            const float4 w2 = *(const float4*)(wr + 2 * NU);
            const float4 w3 = *(const float4*)(wr + 3 * NU);
            fma4(a0, w0, h0v.x); fma4(a1, w0, h1v.x);
            fma4(a0, w1, h0v.y); fma4(a1, w1, h1v.y);
            fma4(a0, w2, h0v.z); fma4(a1, w2, h1v.z);
            fma4(a0, w3, h0v.w); fma4(a1, w3, h1v.w);
        }
        *(float4*)&part[kq][0][uq << 2] = a0;
        *(float4*)&part[kq][1][uq << 2] = a1;
        __syncthreads();

        float z0 = big_, z1 = big_;
        #pragma unroll
        for (int q = 0; q < 4; ++q) { z0 += part[q][0][tid]; z1 += part[q][1][tid]; }

        float zc0 = bc, zo0 = bo, zc1 = bc, zo1 = bo;
        for (int i = 0; i < NS; ++i) {
            const float wc = W_ci[(size_t)i * NU + tid];
            const float wo = W_og[(size_t)i * NU + tid];
            const float s0v = x_lds[0][i];
            const float s1v = x_lds[1][i];
            zc0 = fmaf(s0v, wc, zc0); zo0 = fmaf(s0v, wo, zo0);
            zc1 = fmaf(s1v, wc, zc1); zo1 = fmaf(s1v, wo, zo1);
        }
        const int a0i = a_lds[0], a1i = a_lds[1];
        if (a0i >= 0) { zc0 += W_ci[(size_t)(NS + a0i) * NU + tid]; zo0 += W_og[(size_t)(NS + a0i) * NU + tid]; }
        if (a1i >= 0) { zc1 += W_ci[(size_t)(NS + a1i) * NU + tid]; zo1 += W_og[(size_t)(NS + a1i) * NU + tid]; }
        const float ci0 = tanh_fast(zc0), og0 = sigf(zo0);
        const float ci1 = tanh_fast(zc1), og1 = sigf(zo1);

        const float ig0 = sigf(z0), ig1 = sigf(z1);
        c0 = fmaf(ci0, ig0, c0);
        c1 = fmaf(ci1, ig1, c1);
        const float h0 = c0 * og0, h1 = c1 * og1;
        h_lds[0][tid] = h0;
        h_lds[1][tid] = h1;

        float y0 = h0 * wlin, y1 = h1 * wlin;
        #pragma unroll
        for (int off = 32; off > 0; off >>= 1) {
            y0 += __shfl_xor(y0, off);
            y1 += __shfl_xor(y1, off);
        }
        if ((tid & 63) == 0) { ysum[tid >> 6][0] = y0; ysum[tid >> 6][1] = y1; }
        __syncthreads();

        if (tid < 2) {
            float y = blin;
            #pragma unroll
            for (int w = 0; w < 8; ++w) y += ysum[w][tid];
            out[(size_t)(b0 + tid) * NT1 + t] = y;
        }
    }
}

extern "C" void kernel_launch(void* const* d_in, const int* in_sizes, int n_in,
                              void* d_out, int out_size, void* d_ws, size_t ws_size,
                              hipStream_t stream) {
    const float* states = (const float*)d_in[0];
    const int*   actions= (const int*)d_in[1];
    const float* W_ci = (const float*)d_in[2];
    const float* b_ci = (const float*)d_in[3];
    const float* W_ig = (const float*)d_in[4];
    const float* b_ig = (const float*)d_in[5];
    const float* W_og = (const float*)d_in[6];
    const float* b_og = (const float*)d_in[7];
    const float* W_lin= (const float*)d_in[8];
    const float* b_lin= (const float*)d_in[9];
    float* out = (float*)d_out;

    const size_t need = CIOG_BYTES + (size_t)PACK_SHORTS * 2;   // ~135 MB
    if (ws_size >= need) {
        uint32_t* ciog = (uint32_t*)d_ws;
        short* pack = (short*)((char*)d_ws + CIOG_BYTES);

        (void)hipFuncSetAttribute((const void*)rec_wide,
                                  hipFuncAttributeMaxDynamicSharedMemorySize, DYN_LDS);

        pack_kernel<<<dim3(64), dim3(512), 0, stream>>>(W_ig, pack);
        ff_kernel<<<dim3(NBATCH * 17), dim3(512), 0, stream>>>(
            states, actions, W_ci, b_ci, W_og, b_og, ciog);
        rec_wide<<<dim3(NBATCH / NBW), dim3(1024), DYN_LDS, stream>>>(
            pack, b_ig, W_lin, b_lin, ciog, out);
    } else {
        rec_fallback<<<dim3(NBATCH / 2), dim3(512), 0, stream>>>(
            states, actions, W_ci, b_ci, W_ig, b_ig, W_og, b_og, W_lin, b_lin, out);
    }
}

// Round 20
// 2992.040 us; speedup vs baseline: 1.2577x; 1.2577x over previous
//
#include <hip/hip_runtime.h>
#include <cstdint>

#define NBATCH 128
#define NT 512
#define NT1 513
#define NS 64
#define NU 512
#define NBW 16                               // batches per workgroup
#define KF_SHORTS 16384                      // shorts per kf across the WG (32k x 512u)
#define KF_V8 (KF_SHORTS / 8)                // short8 per kf = 2048
#define PACK_SHORTS (16 * KF_SHORTS)         // 512 KB
#define CIOG_BYTES ((size_t)NT1 * NBATCH * NU * 4)   // [t][b][u]: 134,479,872
#define KF_ST 12                             // kf 0..11 -> L2->VGPR stream (2-slot pipeline)
#define KF_LD 4                              // kf 12..15 -> LDS-resident (128 KB)
#define DYN_LDS (KF_LD * KF_SHORTS * 2)      // 131072 B

typedef __attribute__((ext_vector_type(8))) short short8_t;
typedef __attribute__((ext_vector_type(4))) float f32x4;

__device__ __forceinline__ float sigf(float z) {
    return 1.0f / (1.0f + __expf(-z));
}
__device__ __forceinline__ float tanh_fast(float z) {
    return 2.0f / (1.0f + __expf(-2.0f * z)) - 1.0f;
}
__device__ __forceinline__ uint32_t bf16_top(float f) {   // RNE, result in top 16 bits
    uint32_t u = __float_as_uint(f);
    u += 0x7FFFu + ((u >> 16) & 1u);
    return u & 0xFFFF0000u;
}
__device__ __forceinline__ float f_from_lo(uint32_t p) { return __uint_as_float(p << 16); }
__device__ __forceinline__ float f_from_hi(uint32_t p) { return __uint_as_float(p & 0xFFFF0000u); }

// ---------------------------------------------------------------------------
// pack_kernel (8-wave layout, validated rounds 3-15): W_ig (f32 [k][u]) ->
// bf16 fragment order pack[kf][wv(8)][nf(4)][lane][j].
// value = bf16(W_ig[(kf*32 + (lane>>4)*8 + j)*512 + wv*64 + nf*16 + (lane&15)])
// ---------------------------------------------------------------------------
__global__ __launch_bounds__(512) void pack_kernel(
    const float* __restrict__ W_ig, short* __restrict__ pack)
{
    const int g = blockIdx.x * 512 + threadIdx.x;   // 32768 threads
    const int lane = g & 63;
    const int nf = (g >> 6) & 3;
    const int wv = (g >> 8) & 7;
    const int kf = g >> 11;
    const int r16 = lane & 15, kg = lane >> 4;
    const int u = wv * 64 + nf * 16 + r16;
    const int kb = kf * 32 + kg * 8;
    short8_t w;
    #pragma unroll
    for (int j = 0; j < 8; ++j) {
        w[j] = (short)(bf16_top(W_ig[(size_t)(kb + j) * NU + u]) >> 16);
    }
    *(short8_t*)(pack + (size_t)g * 8) = w;
}

// ---------------------------------------------------------------------------
// ff_kernel: feedforward gates -> packed bf16 (ci lo, og hi), t-major [t][b][u]
// (validated rounds 5-18).
// ---------------------------------------------------------------------------
__global__ __launch_bounds__(512) void ff_kernel(
    const float* __restrict__ states, const int* __restrict__ actions,
    const float* __restrict__ W_ci, const float* __restrict__ b_ci,
    const float* __restrict__ W_og, const float* __restrict__ b_og,
    uint32_t* __restrict__ ciog)
{
    __shared__ __align__(16) float sh_s[32][64];
    __shared__ int sh_a[32];
    const int tid = threadIdx.x;
    const int b = blockIdx.x / 17;
    const int t0 = (blockIdx.x % 17) * 32;
    const int tcnt = (t0 + 32 <= NT1) ? 32 : (NT1 - t0);

    const float* sp = states + ((size_t)b * NT1 + t0) * NS;
    for (int j = tid; j < tcnt * 16; j += 512) {
        const float4 v = *(const float4*)(sp + j * 4);
        *(float4*)&sh_s[j >> 4][(j & 15) * 4] = v;
    }
    for (int tt = tid; tt < tcnt; tt += 512) {
        const int t = t0 + tt;
        sh_a[tt] = (t < NT) ? actions[b * NT + t] : -1;
    }
    __syncthreads();

    const int u = tid;
    float accc[32], acco[32];
    const float bc = b_ci[u], bo = b_og[u];
    #pragma unroll
    for (int tt = 0; tt < 32; ++tt) { accc[tt] = bc; acco[tt] = bo; }

    for (int i = 0; i < NS; ++i) {
        const float wc = W_ci[(size_t)i * NU + u];
        const float wo = W_og[(size_t)i * NU + u];
        #pragma unroll
        for (int tt = 0; tt < 32; ++tt) {
            const float s = sh_s[tt][i];
            accc[tt] = fmaf(s, wc, accc[tt]);
            acco[tt] = fmaf(s, wo, acco[tt]);
        }
    }
    #pragma unroll
    for (int tt = 0; tt < 32; ++tt) {
        if (tt < tcnt) {
            float zc = accc[tt], zo = acco[tt];
            const int a = sh_a[tt];
            if (a >= 0) {
                zc += W_ci[(size_t)(NS + a) * NU + u];
                zo += W_og[(size_t)(NS + a) * NU + u];
            }
            const float ci = tanh_fast(zc);
            const float og = sigf(zo);
            ciog[((size_t)(t0 + tt) * NBATCH + b) * NU + u] = bf16_top(og) | (bf16_top(ci) >> 16);
        }
    }
}

// ---------------------------------------------------------------------------
// rec_stream2 (FINAL, validated round 15: rec 2.78 ms, absmax 0.75):
// 8 WGs x 512 thr (8 waves, 2/SIMD). WG owns 16 batches; wave owns a 64-u
// slice. W supply: kf0..11 streamed L2->VGPR through a TWO-slot rotating
// pipeline (32 regs; distance-2 issue-to-use; wrap refills feed the next
// step since W is t-invariant). kf12..15 LDS-resident (128 KB).
// Design space fully explored (r2-r19): 2 slots is the unique pipeline depth
// that fits the 128-arch-VGPR allocator cap (4 slots spill: r13/r16); 8
// waves optimal (16: conflicts+skew, r18); pk loads mid-stream optimal
// (r17); fp8 weights numerically infeasible (deterministic per-step bias x
// 513 steps: absmax 9.75, r19); cross-CU recurrence needs fences costing
// >=20us/step (r5/r14). h single-buffered LDS, 2 barriers/step.
// ---------------------------------------------------------------------------
__global__ __launch_bounds__(512) void rec_stream2(
    const short* __restrict__ pack,
    const float* __restrict__ b_ig, const float* __restrict__ W_lin,
    const float* __restrict__ b_lin,
    const uint32_t* __restrict__ ciog,   // [t][b][u]
    float* __restrict__ out)
{
    extern __shared__ __align__(16) char dynsm[];      // 128KB: W kf12..15
    __shared__ __align__(16) short hsh[NBW * NU];      // 16KB single buffer
    __shared__ float ysum[2][8][NBW];

    const int tid  = threadIdx.x;
    const int lane = tid & 63;
    const int wv   = tid >> 6;      // wave 0..7, owns u in [wv*64, +64)
    const int n0   = wv << 6;
    const int r16  = lane & 15;
    const int kg   = lane >> 4;
    const int b0   = blockIdx.x * NBW;

    const short8_t* pr = (const short8_t*)pack;
    #define PIDX(KF_, NF_) (((((KF_) * 8) + wv) * 4 + (NF_)) * 64 + lane)
    #define LD4(S_, KF_) { (S_)[0] = pr[PIDX(KF_, 0)]; (S_)[1] = pr[PIDX(KF_, 1)]; \
                           (S_)[2] = pr[PIDX(KF_, 2)]; (S_)[3] = pr[PIDX(KF_, 3)]; }

    // ---- one-time: kf12..15 into LDS (linear copy, layout == pack) ----
    short8_t* dl = (short8_t*)dynsm;
    {
        const short8_t* pl = pr + KF_ST * KF_V8;
        #pragma unroll
        for (int i = 0; i < 16; ++i) dl[i * 512 + tid] = pl[i * 512 + tid];
    }

    float big[4], wl[4];
    #pragma unroll
    for (int nf = 0; nf < 4; ++nf) {
        big[nf] = b_ig[n0 + nf * 16 + r16];
        wl[nf]  = W_lin[n0 + nf * 16 + r16];
    }
    const float blin = b_lin[0];

    for (int i = tid; i < NBW * NU; i += 512) hsh[i] = 0;

    float cst[4][4] = {{0.f,0.f,0.f,0.f},{0.f,0.f,0.f,0.f},
                       {0.f,0.f,0.f,0.f},{0.f,0.f,0.f,0.f}};

    const int amask = (r16 & 7) << 4;    // XOR swizzle (validated r2-r16)
    const char* hb = (const char*)hsh;
    char* hw = (char*)hsh;

    // ---- stream prologue: S0 <- kf0, S1 <- kf1 ----
    short8_t S0[4], S1[4];
    LD4(S0, 0) LD4(S1, 1)

    __syncthreads();

    for (int t = 0; t < NT1; ++t) {
        // previous step's output row (ysum double-buffered)
        if (t > 0 && wv == 0 && lane < NBW) {
            float y = blin;
            #pragma unroll
            for (int w8 = 0; w8 < 8; ++w8) y += ysum[(t - 1) & 1][w8][lane];
            out[(size_t)(b0 + lane) * NT1 + (t - 1)] = y;
        }

        f32x4 acc[4];
        #pragma unroll
        for (int nf = 0; nf < 4; ++nf) { acc[nf][0]=0.f; acc[nf][1]=0.f; acc[nf][2]=0.f; acc[nf][3]=0.f; }

        #define AFRAG(KF) (*(const short8_t*)(hb + r16 * 1024 + ((((KF) * 64) + kg * 16) ^ amask)))
        #define MF4(KF, W) { const short8_t a_ = AFRAG(KF); \
            acc[0] = __builtin_amdgcn_mfma_f32_16x16x32_bf16(a_, (W)[0], acc[0], 0, 0, 0); \
            acc[1] = __builtin_amdgcn_mfma_f32_16x16x32_bf16(a_, (W)[1], acc[1], 0, 0, 0); \
            acc[2] = __builtin_amdgcn_mfma_f32_16x16x32_bf16(a_, (W)[2], acc[2], 0, 0, 0); \
            acc[3] = __builtin_amdgcn_mfma_f32_16x16x32_bf16(a_, (W)[3], acc[3], 0, 0, 0); }

        // ---- streamed phases 0..11: consume slot, refill with kf+2 ----
        MF4(0,  S0)  LD4(S0, 2)
        MF4(1,  S1)  LD4(S1, 3)
        MF4(2,  S0)  LD4(S0, 4)
        MF4(3,  S1)  LD4(S1, 5)
        MF4(4,  S0)  LD4(S0, 6)
        MF4(5,  S1)  LD4(S1, 7)
        MF4(6,  S0)  LD4(S0, 8)
        MF4(7,  S1)  LD4(S1, 9)

        // ci/og loads for this step (mid-stream: latency hidden; validated)
        uint32_t pk[4][4];
        {
            const uint32_t* cg = ciog + (size_t)t * (NBATCH * NU);
            #pragma unroll
            for (int nf = 0; nf < 4; ++nf) {
                #pragma unroll
                for (int j = 0; j < 4; ++j)
                    pk[nf][j] = cg[(size_t)(b0 + kg * 4 + j) * NU + n0 + nf * 16 + r16];
            }
        }

        MF4(8,  S0)  LD4(S0, 10)
        MF4(9,  S1)  LD4(S1, 11)
        MF4(10, S0)  LD4(S0, 0)   // wrap: next step's kf0 (same bytes, W const)
        MF4(11, S1)  LD4(S1, 1)

        // ---- LDS-resident phases kf12..15 ----
        #pragma unroll
        for (int kf = 0; kf < KF_LD; ++kf) {
            short8_t wt[4];
            #pragma unroll
            for (int nf = 0; nf < 4; ++nf)
                wt[nf] = dl[((kf * 8 + wv) * 4 + nf) * 64 + lane];
            MF4(KF_ST + kf, wt)
        }
        #undef MF4
        #undef AFRAG

        __syncthreads();   // barrier 1: all h reads of this step done

        // ---- gate phase: c update, h_{t+1} write (same buffer, now safe) ----
        float yp[4] = {0.f, 0.f, 0.f, 0.f};
        #pragma unroll
        for (int nf = 0; nf < 4; ++nf) {
            const int u2 = (n0 + nf * 16 + r16) * 2;
            #pragma unroll
            for (int j = 0; j < 4; ++j) {
                const int b = kg * 4 + j;
                const float z   = acc[nf][j] + big[nf];
                const float igv = sigf(z);
                const uint32_t p = pk[nf][j];
                cst[nf][j] = fmaf(f_from_lo(p), igv, cst[nf][j]);
                const float hv = cst[nf][j] * f_from_hi(p);
                yp[j] = fmaf(hv, wl[nf], yp[j]);
                const int wb = b * 1024 + (u2 ^ ((b & 7) << 4));
                *(short*)(hw + wb) = (short)(bf16_top(hv) >> 16);
            }
        }

        #pragma unroll
        for (int m = 1; m <= 8; m <<= 1) {
            yp[0] += __shfl_xor(yp[0], m);
            yp[1] += __shfl_xor(yp[1], m);
            yp[2] += __shfl_xor(yp[2], m);
            yp[3] += __shfl_xor(yp[3], m);
        }
        if (r16 == 0) {
            #pragma unroll
            for (int j = 0; j < 4; ++j) ysum[t & 1][wv][kg * 4 + j] = yp[j];
        }

        __syncthreads();   // barrier 2: h_{t+1} + ysum visible
    }

    if (wv == 0 && lane < NBW) {
        float y = blin;
        #pragma unroll
        for (int w8 = 0; w8 < 8; ++w8) y += ysum[0][w8][lane];
        out[(size_t)(b0 + lane) * NT1 + NT] = y;
    }
    #undef LD4
    #undef PIDX
}

// ---------------------------------------------------------------------------
// Fallback (ws too small): validated round-1 kernel.
// ---------------------------------------------------------------------------
__device__ __forceinline__ void fma4(float4& acc, const float4 w, const float s) {
    acc.x = fmaf(w.x, s, acc.x);
    acc.y = fmaf(w.y, s, acc.y);
    acc.z = fmaf(w.z, s, acc.z);
    acc.w = fmaf(w.w, s, acc.w);
}

__global__ __launch_bounds__(512) void rec_fallback(
    const float* __restrict__ states, const int* __restrict__ actions,
    const float* __restrict__ W_ci, const float* __restrict__ b_ci,
    const float* __restrict__ W_ig, const float* __restrict__ b_ig,
    const float* __restrict__ W_og, const float* __restrict__ b_og,
    const float* __restrict__ W_lin, const float* __restrict__ b_lin,
    float* __restrict__ out)
{
    __shared__ __align__(16) float h_lds[2][NU];
    __shared__ __align__(16) float part[4][2][NU];
    __shared__ float ysum[8][2];
    __shared__ float x_lds[2][NS];
    __shared__ int a_lds[2];

    const int tid = threadIdx.x;
    const int b0 = blockIdx.x * 2;
    const int uq = tid & 127;
    const int kq = tid >> 7;
    const int k0 = kq << 7;

    h_lds[0][tid] = 0.0f;
    h_lds[1][tid] = 0.0f;
    float c0 = 0.0f, c1 = 0.0f;
    const float wlin = W_lin[tid];
    const float big_ = b_ig[tid];
    const float blin = b_lin[0];
    const float bc = b_ci[tid], bo = b_og[tid];
    __syncthreads();

    for (int t = 0; t < NT1; ++t) {
        if (tid < 128) {
            const int bb = tid >> 6, i = tid & 63;
            x_lds[bb][i] = states[((size_t)(b0 + bb) * NT1 + t) * NS + i];
        } else if (tid < 130) {
            const int bb = tid - 128;
            a_lds[bb] = (t < NT) ? actions[(b0 + bb) * NT + t] : -1;
        }

        float4 a0 = make_float4(0.f, 0.f, 0.f, 0.f);
        float4 a1 = make_float4(0.f, 0.f, 0.f, 0.f);
        for (int kk = 0; kk < 128; kk += 4) {
            const int k = k0 + kk;
            const float4 h0v = *(const float4*)&h_lds[0][k];
            const float4 h1v = *(const float4*)&h_lds[1][k];
            const float* wr = W_ig + (size_t)k * NU + (uq << 2);
            const float4 w0 = *(const float4*)(wr);
            const float4 w1 = *(const float4*)(wr + NU);
            const float4 w2 = *(const float4*)(wr + 2 * NU);
            const float4 w3 = *(const float4*)(wr + 3 * NU);
            fma4(a0, w0, h0v.x); fma4(a1, w0, h1v.x);
            fma4(a0, w1, h0v.y); fma4(a1, w1, h1v.y);
            fma4(a0, w2, h0v.z); fma4(a1, w2, h1v.z);
            fma4(a0, w3, h0v.w); fma4(a1, w3, h1v.w);
        }
        *(float4*)&part[kq][0][uq << 2] = a0;
        *(float4*)&part[kq][1][uq << 2] = a1;
        __syncthreads();

        float z0 = big_, z1 = big_;
        #pragma unroll
        for (int q = 0; q < 4; ++q) { z0 += part[q][0][tid]; z1 += part[q][1][tid]; }

        float zc0 = bc, zo0 = bo, zc1 = bc, zo1 = bo;
        for (int i = 0; i < NS; ++i) {
            const float wc = W_ci[(size_t)i * NU + tid];
            const float wo = W_og[(size_t)i * NU + tid];
            const float s0v = x_lds[0][i];
            const float s1v = x_lds[1][i];
            zc0 = fmaf(s0v, wc, zc0); zo0 = fmaf(s0v, wo, zo0);
            zc1 = fmaf(s1v, wc, zc1); zo1 = fmaf(s1v, wo, zo1);
        }
        const int a0i = a_lds[0], a1i = a_lds[1];
        if (a0i >= 0) { zc0 += W_ci[(size_t)(NS + a0i) * NU + tid]; zo0 += W_og[(size_t)(NS + a0i) * NU + tid]; }
        if (a1i >= 0) { zc1 += W_ci[(size_t)(NS + a1i) * NU + tid]; zo1 += W_og[(size_t)(NS + a1i) * NU + tid]; }
        const float ci0 = tanh_fast(zc0), og0 = sigf(zo0);
        const float ci1 = tanh_fast(zc1), og1 = sigf(zo1);

        const float ig0 = sigf(z0), ig1 = sigf(z1);
        c0 = fmaf(ci0, ig0, c0);
        c1 = fmaf(ci1, ig1, c1);
        const float h0 = c0 * og0, h1 = c1 * og1;
        h_lds[0][tid] = h0;
        h_lds[1][tid] = h1;

        float y0 = h0 * wlin, y1 = h1 * wlin;
        #pragma unroll
        for (int off = 32; off > 0; off >>= 1) {
            y0 += __shfl_xor(y0, off);
            y1 += __shfl_xor(y1, off);
        }
        if ((tid & 63) == 0) { ysum[tid >> 6][0] = y0; ysum[tid >> 6][1] = y1; }
        __syncthreads();

        if (tid < 2) {
            float y = blin;
            #pragma unroll
            for (int w = 0; w < 8; ++w) y += ysum[w][tid];
            out[(size_t)(b0 + tid) * NT1 + t] = y;
        }
    }
}

extern "C" void kernel_launch(void* const* d_in, const int* in_sizes, int n_in,
                              void* d_out, int out_size, void* d_ws, size_t ws_size,
                              hipStream_t stream) {
    const float* states = (const float*)d_in[0];
    const int*   actions= (const int*)d_in[1];
    const float* W_ci = (const float*)d_in[2];
    const float* b_ci = (const float*)d_in[3];
    const float* W_ig = (const float*)d_in[4];
    const float* b_ig = (const float*)d_in[5];
    const float* W_og = (const float*)d_in[6];
    const float* b_og = (const float*)d_in[7];
    const float* W_lin= (const float*)d_in[8];
    const float* b_lin= (const float*)d_in[9];
    float* out = (float*)d_out;

    const size_t need = CIOG_BYTES + (size_t)PACK_SHORTS * 2;   // ~135 MB
    if (ws_size >= need) {
        uint32_t* ciog = (uint32_t*)d_ws;
        short* pack = (short*)((char*)d_ws + CIOG_BYTES);

        (void)hipFuncSetAttribute((const void*)rec_stream2,
                                  hipFuncAttributeMaxDynamicSharedMemorySize, DYN_LDS);

        pack_kernel<<<dim3(64), dim3(512), 0, stream>>>(W_ig, pack);
        ff_kernel<<<dim3(NBATCH * 17), dim3(512), 0, stream>>>(
            states, actions, W_ci, b_ci, W_og, b_og, ciog);
        rec_stream2<<<dim3(NBATCH / NBW), dim3(512), DYN_LDS, stream>>>(
            pack, b_ig, W_lin, b_lin, ciog, out);
    } else {
        rec_fallback<<<dim3(NBATCH / 2), dim3(512), 0, stream>>>(
            states, actions, W_ci, b_ci, W_ig, b_ig, W_og, b_og, W_lin, b_lin, out);
    }
}